// Round 3
// baseline (48.397 us; speedup 1.0000x reference)
//
#include <hip/hip_runtime.h>
#include <math.h>

// out[i][j] for x=qx1[i], y=qx2[j], a=x^2, b=y^2:
//   u    = exp(-(a + 2b + 1))
//   out  = u*(7 + a + 28b) - u^2*(4a + 16b)*(1 + 2b)
// Separable: row vec r={ex*(7+a), ex, ex^2*a, ex^2}, ex=exp(-1-a)
//            col vec c={ey, 28b*ey, 4*ey^2*(1+2b), 16b*ey^2*(1+2b)}, ey=exp(-2b)
//   out = r.x*c.x + r.y*c.y - r.z*c.z - r.w*c.w
//
// Pure HBM-write-bound: 256 MiB out, 64 KiB in. Measured write ceiling on
// this chip (harness fillBuffer dispatches): ~7.1 TB/s -> ~38 us floor.

typedef float floatx4 __attribute__((ext_vector_type(4)));  // clang vector: valid for nontemporal builtin

#define COLS_PER_BLOCK 1024
#define ROWS_PER_BLOCK 32
#define NTHREADS 256

__global__ __launch_bounds__(NTHREADS) void pde_grid_kernel(
    const float* __restrict__ qx1,
    const float* __restrict__ qx2,
    float* __restrict__ out,
    int N1, int N2)
{
    __shared__ float4 sRow[ROWS_PER_BLOCK];

    const int t = threadIdx.x;
    const int colTiles = N2 / COLS_PER_BLOCK;          // 8 for N2=8192
    const int bidC = blockIdx.x % colTiles;
    const int bidR = blockIdx.x / colTiles;
    const int col0 = bidC * COLS_PER_BLOCK;
    const int row0 = bidR * ROWS_PER_BLOCK;

    // ---- Row coefficient table (first ROWS_PER_BLOCK threads), shared.
    if (t < ROWS_PER_BLOCK) {
        const float x   = qx1[row0 + t];
        const float a   = x * x;
        const float ex  = expf(-1.0f - a);
        const float ex2 = ex * ex;
        sRow[t] = make_float4(ex * (7.0f + a), ex, ex2 * a, ex2);
    }

    // ---- This thread's 4 column coefficients: straight into registers.
    const float4 y4 = *reinterpret_cast<const float4*>(qx2 + col0 + 4 * t);
    float4 P, Q, R, S;
    {
        const float ys[4] = {y4.x, y4.y, y4.z, y4.w};
        float p[4], q[4], rr[4], ss[4];
#pragma unroll
        for (int k = 0; k < 4; ++k) {
            const float y   = ys[k];
            const float b   = y * y;
            const float ey  = expf(-2.0f * b);
            const float ey2 = ey * ey;
            const float w   = 1.0f + 2.0f * b;
            p[k]  = ey;
            q[k]  = 28.0f * b * ey;
            rr[k] = 4.0f * ey2 * w;
            ss[k] = 16.0f * b * ey2 * w;
        }
        P = make_float4(p[0], p[1], p[2], p[3]);
        Q = make_float4(q[0], q[1], q[2], q[3]);
        R = make_float4(rr[0], rr[1], rr[2], rr[3]);
        S = make_float4(ss[0], ss[1], ss[2], ss[3]);
    }

    __syncthreads();

    float* op = out + (size_t)row0 * (size_t)N2 + col0 + 4 * t;

#pragma unroll 4
    for (int r = 0; r < ROWS_PER_BLOCK; ++r) {
        const float4 rv = sRow[r];   // broadcast read, conflict-free
        floatx4 o;
        o.x = fmaf(rv.x, P.x, fmaf(rv.y, Q.x, -fmaf(rv.z, R.x, rv.w * S.x)));
        o.y = fmaf(rv.x, P.y, fmaf(rv.y, Q.y, -fmaf(rv.z, R.y, rv.w * S.y)));
        o.z = fmaf(rv.x, P.z, fmaf(rv.y, Q.z, -fmaf(rv.z, R.z, rv.w * S.z)));
        o.w = fmaf(rv.x, P.w, fmaf(rv.y, Q.w, -fmaf(rv.z, R.w, rv.w * S.w)));
        __builtin_nontemporal_store(o, reinterpret_cast<floatx4*>(op));
        op += N2;
    }
}

extern "C" void kernel_launch(void* const* d_in, const int* in_sizes, int n_in,
                              void* d_out, int out_size, void* d_ws, size_t ws_size,
                              hipStream_t stream) {
    const float* qx1 = (const float*)d_in[0];
    const float* qx2 = (const float*)d_in[1];
    // param_a (d_in[2]) is unused by the reference expression.
    float* out = (float*)d_out;

    const int N1 = in_sizes[0];   // 8192
    const int N2 = in_sizes[1];   // 8192

    const int colTiles = N2 / COLS_PER_BLOCK;   // 8
    const int rowTiles = N1 / ROWS_PER_BLOCK;   // 256
    dim3 grid(colTiles * rowTiles);             // 2048 blocks
    dim3 block(NTHREADS);

    pde_grid_kernel<<<grid, block, 0, stream>>>(qx1, qx2, out, N1, N2);
}

// Round 4
// 46.225 us; speedup vs baseline: 1.0470x; 1.0470x over previous
//
#include <hip/hip_runtime.h>
#include <math.h>

// out[i][j] for x=qx1[i], y=qx2[j], a=x^2, b=y^2:
//   u    = exp(-(a + 2b + 1))
//   out  = u*(7 + a + 28b) - u^2*(4a + 16b)*(1 + 2b)
// Separable: row vec r={ex*(7+a), ex, ex^2*a, ex^2}, ex=exp(-1-a)
//            col vec c={ey, 28b*ey, 4*ey^2*(1+2b), 16b*ey^2*(1+2b)}, ey=exp(-2b)
//   out = r.x*c.x + r.y*c.y - r.z*c.z - r.w*c.w
//
// Pure HBM-write-bound: 256 MiB out, 64 KiB in.
// Model from fills + R1/R3: t = bytes/7.6TBps + ~12us fixed  ->  ~47.4 us.

#define COLS_PER_BLOCK 1024
#define ROWS_PER_BLOCK 64
#define NTHREADS 256

__global__ __launch_bounds__(NTHREADS) void pde_grid_kernel(
    const float* __restrict__ qx1,
    const float* __restrict__ qx2,
    float* __restrict__ out,
    int N1, int N2)
{
    __shared__ float4 sRow[ROWS_PER_BLOCK];

    const int t = threadIdx.x;
    const int colTiles = N2 / COLS_PER_BLOCK;          // 8 for N2=8192
    const int bidC = blockIdx.x % colTiles;
    const int bidR = blockIdx.x / colTiles;
    const int col0 = bidC * COLS_PER_BLOCK;
    const int row0 = bidR * ROWS_PER_BLOCK;

    // ---- Row coefficient table (first ROWS_PER_BLOCK threads), shared.
    if (t < ROWS_PER_BLOCK) {
        const float x   = qx1[row0 + t];
        const float a   = x * x;
        const float ex  = __expf(-1.0f - a);
        const float ex2 = ex * ex;
        sRow[t] = make_float4(ex * (7.0f + a), ex, ex2 * a, ex2);
    }

    // ---- This thread's 4 column coefficients: straight into registers.
    const float4 y4 = *reinterpret_cast<const float4*>(qx2 + col0 + 4 * t);
    float4 P, Q, R, S;
    {
        const float ys[4] = {y4.x, y4.y, y4.z, y4.w};
        float p[4], q[4], rr[4], ss[4];
#pragma unroll
        for (int k = 0; k < 4; ++k) {
            const float y   = ys[k];
            const float b   = y * y;
            const float ey  = __expf(-2.0f * b);
            const float ey2 = ey * ey;
            const float w   = 1.0f + 2.0f * b;
            p[k]  = ey;
            q[k]  = 28.0f * b * ey;
            rr[k] = 4.0f * ey2 * w;
            ss[k] = 16.0f * b * ey2 * w;
        }
        P = make_float4(p[0], p[1], p[2], p[3]);
        Q = make_float4(q[0], q[1], q[2], q[3]);
        R = make_float4(rr[0], rr[1], rr[2], rr[3]);
        S = make_float4(ss[0], ss[1], ss[2], ss[3]);
    }

    __syncthreads();

    float* op = out + (size_t)row0 * (size_t)N2 + col0 + 4 * t;

#pragma unroll 4
    for (int r = 0; r < ROWS_PER_BLOCK; ++r) {
        const float4 rv = sRow[r];   // broadcast read, conflict-free
        float4 o;
        o.x = fmaf(rv.x, P.x, fmaf(rv.y, Q.x, -fmaf(rv.z, R.x, rv.w * S.x)));
        o.y = fmaf(rv.x, P.y, fmaf(rv.y, Q.y, -fmaf(rv.z, R.y, rv.w * S.y)));
        o.z = fmaf(rv.x, P.z, fmaf(rv.y, Q.z, -fmaf(rv.z, R.z, rv.w * S.z)));
        o.w = fmaf(rv.x, P.w, fmaf(rv.y, Q.w, -fmaf(rv.z, R.w, rv.w * S.w)));
        *reinterpret_cast<float4*>(op) = o;
        op += N2;
    }
}

extern "C" void kernel_launch(void* const* d_in, const int* in_sizes, int n_in,
                              void* d_out, int out_size, void* d_ws, size_t ws_size,
                              hipStream_t stream) {
    const float* qx1 = (const float*)d_in[0];
    const float* qx2 = (const float*)d_in[1];
    // param_a (d_in[2]) is unused by the reference expression.
    float* out = (float*)d_out;

    const int N1 = in_sizes[0];   // 8192
    const int N2 = in_sizes[1];   // 8192

    const int colTiles = N2 / COLS_PER_BLOCK;   // 8
    const int rowTiles = N1 / ROWS_PER_BLOCK;   // 128
    dim3 grid(colTiles * rowTiles);             // 1024 blocks
    dim3 block(NTHREADS);

    pde_grid_kernel<<<grid, block, 0, stream>>>(qx1, qx2, out, N1, N2);
}